// Round 14
// baseline (216.768 us; speedup 1.0000x reference)
//
#include <hip/hip_runtime.h>

typedef __attribute__((ext_vector_type(8))) __bf16 bf16x8;
typedef __attribute__((ext_vector_type(4))) float f32x4;
typedef __attribute__((ext_vector_type(16))) float f32x16;
typedef unsigned short u16;

// Problem constants
#define TSEQ   2048
#define NB     4
#define NHEAD  16
#define HDIM   64
#define CMODEL 1024
#define MTOK   (NB*TSEQ)          // 8192 tokens

__device__ __forceinline__ u16 f2bf(float x){
  unsigned u = __float_as_uint(x);
  u += 0x7fffu + ((u >> 16) & 1u);          // RNE (no NaN inputs here)
  return (u16)(u >> 16);
}

// pack 2 f32 -> u32 of 2 bf16 (lo in low 16), RNE
__device__ __forceinline__ unsigned cvtpk(float lo, float hi){
  unsigned r;
  asm("v_cvt_pk_bf16_f32 %0, %1, %2" : "=v"(r) : "v"(lo), "v"(hi));
  return r;
}
// v_permlane32_swap: a.lanes[32:63] <-> b.lanes[0:31]
__device__ __forceinline__ void plswap(unsigned &a, unsigned &b){
  asm volatile("v_permlane32_swap_b32 %0, %1" : "+v"(a), "+v"(b));
}

// async global->LDS, 16B per lane. lds_base must be wave-uniform (affine in
// lane with 16B slope); HW writes lane i at base + i*16.
__device__ __forceinline__ void async16(const void* g, const u16* lds_base){
  __builtin_amdgcn_global_load_lds(
      (const __attribute__((address_space(1))) unsigned*)(uintptr_t)g,
      (__attribute__((address_space(3))) unsigned*)(unsigned)(uintptr_t)lds_base,
      16, 0, 0);
}

// ---------------------------------------------------------------------------
// prep kernels
// ---------------------------------------------------------------------------
__global__ void cast_bf16_kernel(const float* __restrict__ src, u16* __restrict__ dst, int n4){
  int i = blockIdx.x * blockDim.x + threadIdx.x;
  int stride = gridDim.x * blockDim.x;
  for (; i < n4; i += stride){
    float4 v = ((const float4*)src)[i];
    ((ushort4*)dst)[i] = make_ushort4(f2bf(v.x), f2bf(v.y), f2bf(v.z), f2bf(v.w));
  }
}

__global__ void cast4_bf16_kernel(const float* __restrict__ s0, const float* __restrict__ s1,
                                  const float* __restrict__ s2, const float* __restrict__ s3,
                                  u16* __restrict__ d0, u16* __restrict__ d1,
                                  u16* __restrict__ d2, u16* __restrict__ d3, int n4){
  int which = blockIdx.y;
  const float* s = (which==0)?s0:(which==1)?s1:(which==2)?s2:s3;
  u16* d        = (which==0)?d0:(which==1)?d1:(which==2)?d2:d3;
  int i = blockIdx.x * blockDim.x + threadIdx.x;
  int stride = gridDim.x * blockDim.x;
  for (; i < n4; i += stride){
    float4 v = ((const float4*)s)[i];
    ((ushort4*)d)[i] = make_ushort4(f2bf(v.x), f2bf(v.y), f2bf(v.z), f2bf(v.w));
  }
}

__global__ void rope_table_kernel(float2* __restrict__ rope){
  int i = blockIdx.x * blockDim.x + threadIdx.x;       // T * HDIM/2 = 2048*32
  if (i >= TSEQ * (HDIM/2)) return;
  int t = i >> 5, j = i & 31;
  float theta = exp2f(-(float)j * (13.287712379549449f / 32.f));
  float ang = (float)t * theta;
  rope[i] = make_float2(cosf(ang), sinf(ang));
}

// ---------------------------------------------------------------------------
// 128x256 tile GEMM, triple-buffered BK=64, counted vmcnt pipeline (round-12,
// verified). 512 thr / 8 waves (2M x 4N); per-wave 64x64 out, acc[4][4].
// ---------------------------------------------------------------------------
#define AREG 8192    // u16 per A buf (128*64)
#define BREG 16384   // u16 per B buf (256*64)

__device__ __forceinline__ void gemm_tb3_mainloop(
    const u16* __restrict__ A, const u16* __restrict__ B,
    int m0, int n0, u16* sAb, u16* sBb, f32x4 acc[4][4])
{
  const int tid = threadIdx.x;
  const int lane = tid & 63, w = tid >> 6;
  const int ln = lane & 15, g = lane >> 4;
  const int wm = w >> 2, wn = w & 3;

  const f32x4 zero = {0.f, 0.f, 0.f, 0.f};
#pragma unroll
  for (int i = 0; i < 4; ++i)
#pragma unroll
    for (int nt = 0; nt < 4; ++nt) acc[i][nt] = zero;

  const int cA0 = tid,       rA0 = cA0 >> 3;
  const int cA1 = 512 + tid, rA1 = cA1 >> 3;
  const u16* aS0 = A + (size_t)(m0 + rA0)*CMODEL + (((cA0 & 7) ^ (rA0 & 7)) << 3);
  const u16* aS1 = A + (size_t)(m0 + rA1)*CMODEL + (((cA1 & 7) ^ (rA1 & 7)) << 3);
  const unsigned dA0 = (unsigned)cA0 * 8, dA1 = (unsigned)cA1 * 8;
  const u16* bS[4]; unsigned dB[4];
#pragma unroll
  for (int j = 0; j < 4; ++j){
    int c = j*512 + tid, r = c >> 3;
    bS[j] = B + (size_t)(n0 + r)*CMODEL + (((c & 7) ^ (r & 7)) << 3);
    dB[j] = (unsigned)c * 8;
  }

  unsigned aoff[4][2], boff[4][2];
#pragma unroll
  for (int i = 0; i < 4; ++i){
    int r = wm*64 + i*16 + ln;
#pragma unroll
    for (int kk = 0; kk < 2; ++kk)
      aoff[i][kk] = (unsigned)(r*8 + ((kk*4 + g) ^ (r & 7))) * 8;
  }
#pragma unroll
  for (int nt = 0; nt < 4; ++nt){
    int r = wn*64 + nt*16 + ln;
#pragma unroll
    for (int kk = 0; kk < 2; ++kk)
      boff[nt][kk] = (unsigned)(r*8 + ((kk*4 + g) ^ (r & 7))) * 8;
  }

  async16(aS0,       sAb + dA0);
  async16(aS1,       sAb + dA1);
  async16(bS[0],     sBb + dB[0]);
  async16(bS[1],     sBb + dB[1]);
  async16(bS[2],     sBb + dB[2]);
  async16(bS[3],     sBb + dB[3]);
  async16(aS0 + 64,  sAb + AREG + dA0);
  async16(aS1 + 64,  sAb + AREG + dA1);
  async16(bS[0] + 64, sBb + BREG + dB[0]);
  async16(bS[1] + 64, sBb + BREG + dB[1]);
  async16(bS[2] + 64, sBb + BREG + dB[2]);
  async16(bS[3] + 64, sBb + BREG + dB[3]);
  asm volatile("s_waitcnt vmcnt(6)" ::: "memory");
  asm volatile("s_barrier" ::: "memory");

#pragma unroll 1
  for (int kt = 0; kt < 16; ++kt){
    const int cb = kt % 3;
    const int nb = (kt + 2) % 3;
    const u16* Ab = sAb + cb*AREG;
    const u16* Bb = sBb + cb*BREG;
    u16* An = sAb + nb*AREG;
    u16* Bn = sBb + nb*BREG;
    const unsigned ko = (unsigned)(kt + 2) * 64u;
    const bool st = (kt < 14);

    bf16x8 a0, a1, a2, a3, b0, b1, b2, b3;

    a0 = *(const bf16x8*)&Ab[aoff[0][0]];
    a1 = *(const bf16x8*)&Ab[aoff[1][0]];
    b0 = *(const bf16x8*)&Bb[boff[0][0]];
    b1 = *(const bf16x8*)&Bb[boff[1][0]];
    b2 = *(const bf16x8*)&Bb[boff[2][0]];
    b3 = *(const bf16x8*)&Bb[boff[3][0]];
    if (st){ async16(aS0 + ko, An + dA0); async16(aS1 + ko, An + dA1); }
    asm volatile("s_barrier" ::: "memory");
    __builtin_amdgcn_s_setprio(1);
    acc[0][0] = __builtin_amdgcn_mfma_f32_16x16x32_bf16(a0, b0, acc[0][0], 0,0,0);
    acc[0][1] = __builtin_amdgcn_mfma_f32_16x16x32_bf16(a0, b1, acc[0][1], 0,0,0);
    acc[0][2] = __builtin_amdgcn_mfma_f32_16x16x32_bf16(a0, b2, acc[0][2], 0,0,0);
    acc[0][3] = __builtin_amdgcn_mfma_f32_16x16x32_bf16(a0, b3, acc[0][3], 0,0,0);
    acc[1][0] = __builtin_amdgcn_mfma_f32_16x16x32_bf16(a1, b0, acc[1][0], 0,0,0);
    acc[1][1] = __builtin_amdgcn_mfma_f32_16x16x32_bf16(a1, b1, acc[1][1], 0,0,0);
    acc[1][2] = __builtin_amdgcn_mfma_f32_16x16x32_bf16(a1, b2, acc[1][2], 0,0,0);
    acc[1][3] = __builtin_amdgcn_mfma_f32_16x16x32_bf16(a1, b3, acc[1][3], 0,0,0);
    __builtin_amdgcn_s_setprio(0);
    asm volatile("s_barrier" ::: "memory");

    a2 = *(const bf16x8*)&Ab[aoff[2][0]];
    a3 = *(const bf16x8*)&Ab[aoff[3][0]];
    if (st){ async16(bS[0] + ko, Bn + dB[0]); async16(bS[1] + ko, Bn + dB[1]); }
    asm volatile("s_barrier" ::: "memory");
    __builtin_amdgcn_s_setprio(1);
    acc[2][0] = __builtin_amdgcn_mfma_f32_16x16x32_bf16(a2, b0, acc[2][0], 0,0,0);
    acc[2][1] = __builtin_amdgcn_mfma_f32_16x16x32_bf16(a2, b1, acc[2][1], 0,0,0);
    acc[2][2] = __builtin_amdgcn_mfma_f32_16x16x32_bf16(a2, b2, acc[2][2], 0,0,0);
    acc[2][3] = __builtin_amdgcn_mfma_f32_16x16x32_bf16(a2, b3, acc[2][3], 0,0,0);
    acc[3][0] = __builtin_amdgcn_mfma_f32_16x16x32_bf16(a3, b0, acc[3][0], 0,0,0);
    acc[3][1] = __builtin_amdgcn_mfma_f32_16x16x32_bf16(a3, b1, acc[3][1], 0,0,0);
    acc[3][2] = __builtin_amdgcn_mfma_f32_16x16x32_bf16(a3, b2, acc[3][2], 0,0,0);
    acc[3][3] = __builtin_amdgcn_mfma_f32_16x16x32_bf16(a3, b3, acc[3][3], 0,0,0);
    __builtin_amdgcn_s_setprio(0);
    asm volatile("s_barrier" ::: "memory");

    a0 = *(const bf16x8*)&Ab[aoff[0][1]];
    a1 = *(const bf16x8*)&Ab[aoff[1][1]];
    b0 = *(const bf16x8*)&Bb[boff[0][1]];
    b1 = *(const bf16x8*)&Bb[boff[1][1]];
    b2 = *(const bf16x8*)&Bb[boff[2][1]];
    b3 = *(const bf16x8*)&Bb[boff[3][1]];
    if (st) async16(bS[2] + ko, Bn + dB[2]);
    asm volatile("s_barrier" ::: "memory");
    __builtin_amdgcn_s_setprio(1);
    acc[0][0] = __builtin_amdgcn_mfma_f32_16x16x32_bf16(a0, b0, acc[0][0], 0,0,0);
    acc[0][1] = __builtin_amdgcn_mfma_f32_16x16x32_bf16(a0, b1, acc[0][1], 0,0,0);
    acc[0][2] = __builtin_amdgcn_mfma_f32_16x16x32_bf16(a0, b2, acc[0][2], 0,0,0);
    acc[0][3] = __builtin_amdgcn_mfma_f32_16x16x32_bf16(a0, b3, acc[0][3], 0,0,0);
    acc[1][0] = __builtin_amdgcn_mfma_f32_16x16x32_bf16(a1, b0, acc[1][0], 0,0,0);
    acc[1][1] = __builtin_amdgcn_mfma_f32_16x16x32_bf16(a1, b1, acc[1][1], 0,0,0);
    acc[1][2] = __builtin_amdgcn_mfma_f32_16x16x32_bf16(a1, b2, acc[1][2], 0,0,0);
    acc[1][3] = __builtin_amdgcn_mfma_f32_16x16x32_bf16(a1, b3, acc[1][3], 0,0,0);
    __builtin_amdgcn_s_setprio(0);
    asm volatile("s_barrier" ::: "memory");

    a2 = *(const bf16x8*)&Ab[aoff[2][1]];
    a3 = *(const bf16x8*)&Ab[aoff[3][1]];
    if (st) async16(bS[3] + ko, Bn + dB[3]);
    asm volatile("s_barrier" ::: "memory");
    __builtin_amdgcn_s_setprio(1);
    acc[2][0] = __builtin_amdgcn_mfma_f32_16x16x32_bf16(a2, b0, acc[2][0], 0,0,0);
    acc[2][1] = __builtin_amdgcn_mfma_f32_16x16x32_bf16(a2, b1, acc[2][1], 0,0,0);
    acc[2][2] = __builtin_amdgcn_mfma_f32_16x16x32_bf16(a2, b2, acc[2][2], 0,0,0);
    acc[2][3] = __builtin_amdgcn_mfma_f32_16x16x32_bf16(a2, b3, acc[2][3], 0,0,0);
    acc[3][0] = __builtin_amdgcn_mfma_f32_16x16x32_bf16(a3, b0, acc[3][0], 0,0,0);
    acc[3][1] = __builtin_amdgcn_mfma_f32_16x16x32_bf16(a3, b1, acc[3][1], 0,0,0);
    acc[3][2] = __builtin_amdgcn_mfma_f32_16x16x32_bf16(a3, b2, acc[3][2], 0,0,0);
    acc[3][3] = __builtin_amdgcn_mfma_f32_16x16x32_bf16(a3, b3, acc[3][3], 0,0,0);
    __builtin_amdgcn_s_setprio(0);
    if (st) asm volatile("s_waitcnt vmcnt(6)" ::: "memory");
    else    asm volatile("s_waitcnt vmcnt(0)" ::: "memory");
    asm volatile("s_barrier" ::: "memory");
  }
}

// ---------------------------------------------------------------------------
// QKV projection (128x256 tb3) + bias + RoPE(Q,K) + head-split; V transposed.
// ---------------------------------------------------------------------------
#define SCQ 0.18033688011112042f   // 0.125 * log2(e)

__global__ __launch_bounds__(512, 1) void gemm_qkv_kernel(
    const u16* __restrict__ xb,
    const u16* __restrict__ wqb, const u16* __restrict__ wkb, const u16* __restrict__ wvb,
    const float* __restrict__ bq, const float* __restrict__ bk, const float* __restrict__ bv,
    const float2* __restrict__ rope,
    u16* __restrict__ Qh, u16* __restrict__ Kh, u16* __restrict__ Vt)
{
  __shared__ u16 sA[3*AREG];
  __shared__ u16 sB[3*BREG];
  const int z = blockIdx.z;
  const u16*  W    = (z == 0) ? wqb : (z == 1) ? wkb : wvb;
  const float* bias = (z == 0) ? bq  : (z == 1) ? bk  : bv;
  const int m0 = blockIdx.y * 128, n0 = blockIdx.x * 256;

  f32x4 acc[4][4];
  gemm_tb3_mainloop(xb, W, m0, n0, sA, sB, acc);

  const int tid = threadIdx.x, w = tid >> 6, lane = tid & 63;
  const int ln = lane & 15, g = lane >> 4;
  const int wm = w >> 2, wn = w & 3;

#pragma unroll
  for (int mt = 0; mt < 4; ++mt){
#pragma unroll
    for (int nt = 0; nt < 4; ++nt){
      int o  = n0 + wn*64 + nt*16 + ln;    // output feature 0..1023
      float bb = bias[o];
      int h  = o >> 6;
      int dd = o & 63;
      if (z < 2){
        int j = dd >> 1;
        u16* dst = (z == 0) ? Qh : Kh;
        float qs = (z == 0) ? SCQ : 1.0f;
#pragma unroll
        for (int rr = 0; rr < 4; ++rr){
          int t  = m0 + wm*64 + mt*16 + g*4 + rr;   // global token
          int b  = t >> 11, tt = t & (TSEQ-1);
          float v  = acc[mt][nt][rr] + bb;
          float pv = __shfl_xor(v, 1);              // rope partner (o^1), same row
          float2 cs = rope[tt*32 + j];
          float out = ((o & 1) == 0) ? (v*cs.x - pv*cs.y) : (pv*cs.y + v*cs.x);
          dst[(size_t)((b*NHEAD + h)*TSEQ + tt)*HDIM + dd] = f2bf(out * qs);
        }
      } else {
        int t0 = m0 + wm*64 + mt*16 + g*4;
        int b  = t0 >> 11, tt0 = t0 & (TSEQ-1);
        u16 pk[4];
#pragma unroll
        for (int rr = 0; rr < 4; ++rr) pk[rr] = f2bf(acc[mt][nt][rr] + bb);
        *(ushort4*)&Vt[(size_t)((b*NHEAD + h)*HDIM + dd)*TSEQ + tt0] =
            make_ushort4(pk[0], pk[1], pk[2], pk[3]);
      }
    }
  }
}

// ---------------------------------------------------------------------------
// Flash attention v12: KVBLK=32, TRIPLE-buffered K/V with counted vmcnt —
// prefetch 2 tiles ahead, never drain to 0 in the main loop (T4/AITER).
// Order per iter: [vmcnt(4|0); s_barrier; stage jt+2 -> buf (jt+2)%3;
// compute buf jt%3]. Ledger: 4 loads/thread/tile, in-order retirement;
// vmcnt(4) at top of jt proves jt's loads landed with a 2-tile latency
// budget (~1000cy >= 900cy HBM miss). WAR: stage of buf (jt-1)%3 issued
// after the barrier that ends jt-1's reads of it.
// ---------------------------------------------------------------------------
__global__ __launch_bounds__(128) void attn_kernel(
    const u16* __restrict__ Qh, const u16* __restrict__ Kh,
    const u16* __restrict__ Vt, u16* __restrict__ yb)
{
  __shared__ u16 sK[3][32*64];
  __shared__ u16 sV[3][64*32];

  const int tid = threadIdx.x, w = tid >> 6, lane = tid & 63;
  const int ln = lane & 31, hi = lane >> 5;

  const int bid = blockIdx.x;
  const int t   = 31 - (bid >> 6);           // 64-row q-tile, longest first
  const int bh  = (bid & 7) * 8 + ((bid >> 3) & 7);
  const int b   = bh >> 4, h = bh & (NHEAD-1);

  const u16* Qbase = Qh + (size_t)bh * TSEQ * HDIM;
  const u16* Kbase = Kh + (size_t)bh * TSEQ * HDIM;
  const u16* Vbase = Vt + (size_t)bh * HDIM * TSEQ;

  const int r0  = t*64 + w*32;               // this wave's first q-row
  const int jtw = 2*t + w;                   // wave's diagonal 32-kv tile
  const int jtb = 2*t + 1;                   // block's last tile

  const f32x16 zero16 = {0,0,0,0,0,0,0,0,0,0,0,0,0,0,0,0};

  // staging: K chunks c=i*128+tid (r=c>>3, s=c&7); V chunks (r=c>>2, s=c&3)
  const u16* kp[2]; const u16* vp[2]; unsigned kd[2];
#pragma unroll
  for (int i = 0; i < 2; ++i){
    int c = i*128 + tid;
    int kr = c >> 3, ks = c & 7;
    kp[i] = Kbase + (size_t)kr*HDIM + ((ks ^ (kr&7))<<3);
    int vr = c >> 2, vs = c & 3;
    vp[i] = Vbase + (size_t)vr*TSEQ + ((vs ^ (vr&3))<<3);
    kd[i] = (unsigned)c * 8;                 // same dst offset for K and V bufs
  }

  // frag read offsets (u16 units)
  unsigned koff[4];
#pragma unroll
  for (int ds = 0; ds < 4; ++ds)
    koff[ds] = (unsigned)(ln*8 + ((2*ds + hi) ^ (ln & 7))) * 8;
  unsigned voff0[2], voff1[2];
#pragma unroll
  for (int st = 0; st < 2; ++st){
    unsigned ch = (unsigned)((2*st + hi) ^ (ln & 3)) * 8;
    voff0[st] = (unsigned)ln*32 + ch;
    voff1[st] = (unsigned)(32+ln)*32 + ch;
  }

  // Q fragments: lane ln holds Q[r0+ln][ds*16 + hi*8 .. +8]
  bf16x8 qf[4];
#pragma unroll
  for (int ds = 0; ds < 4; ++ds)
    qf[ds] = *(const bf16x8*)&Qbase[(size_t)(r0 + ln)*HDIM + ds*16 + hi*8];

  f32x16 yacc0 = zero16, yacc1 = zero16;
  float m2 = -1e30f, lp = 0.f;

  // prologue: stage tile 0 -> buf0, tile 1 -> buf1 (jtb >= 1 always)
#pragma unroll
  for (int i = 0; i < 2; ++i){
    async16(kp[i], sK[0] + kd[i]);
    async16(vp[i], sV[0] + kd[i]);
  }
  {
    const size_t ko = (size_t)(32*HDIM);
    const size_t vo = 32;
#pragma unroll
    for (int i = 0; i < 2; ++i){
      async16(kp[i] + ko, sK[1] + kd[i]);
      async16(vp[i] + vo, sV[1] + kd[i]);
    }
  }

#pragma unroll 1
  for (int jt = 0; jt <= jtb; ++jt){
    // RAW gate: jt's loads (issued 2 iters ago) must be done.
    if (jt < jtb) asm volatile("s_waitcnt vmcnt(4)" ::: "memory");
    else          asm volatile("s_waitcnt vmcnt(0)" ::: "memory");
    asm volatile("s_barrier" ::: "memory");

    // stage jt+2 into buf (jt+2)%3  (safe: its last readers finished at the
    // barrier above; its next readers gated by vmcnt at top of jt+2)
    if (jt + 2 <= jtb){
      const int nb = (jt + 2) % 3;
      const size_t ko = (size_t)(jt+2) * (32*HDIM);
      const size_t vo = (size_t)(jt+2) * 32;
      u16* sKb = sK[nb]; u16* sVb = sV[nb];
#pragma unroll
      for (int i = 0; i < 2; ++i){
        async16(kp[i] + ko, sKb + kd[i]);
        async16(vp[i] + vo, sVb + kd[i]);
      }
    }

    if (jt <= jtw){
      const int cb = jt % 3;
      const u16* sKb = sK[cb];
      const u16* sVb = sV[cb];

      // ---- QK^T (swapped): p0 = S^T, 32 kv rows x 32 q cols ----
      f32x16 p0 = zero16;
      __builtin_amdgcn_s_setprio(1);
#pragma unroll
      for (int ds = 0; ds < 4; ++ds){
        bf16x8 k0 = *(const bf16x8*)&sKb[koff[ds]];
        p0 = __builtin_amdgcn_mfma_f32_32x32x16_bf16(k0, qf[ds], p0, 0, 0, 0);
      }
      __builtin_amdgcn_s_setprio(0);

      // ---- causal mask on the wave's diagonal tile ----
      if (jt == jtw){
#pragma unroll
        for (int r = 0; r < 16; ++r){
          int k0r = (r&3) + 8*(r>>2) + 4*hi;
          if (k0r > ln) p0[r] = -1e30f;
        }
      }

      // ---- lane-local row max over own 16 values ----
      float lm = p0[0];
#pragma unroll
      for (int r = 1; r < 16; ++r) lm = fmaxf(lm, p0[r]);

      // defer-max: rescale only when some row max grows by >8 (log2 units)
      if (__any(lm - m2 > 8.0f)){
        float lmp = __shfl_xor(lm, 32);
        float mn  = fmaxf(m2, fmaxf(lm, lmp));
        float scl = exp2f(m2 - mn);
        m2 = mn;
        lp *= scl;
#pragma unroll
        for (int r = 0; r < 16; ++r){
          float sr = __shfl(scl, (r&3) + 8*(r>>2) + 4*hi);  // scl lives at lane q
          yacc0[r] *= sr; yacc1[r] *= sr;
        }
      }

      // ---- exp + per-lane partial sum ----
      float ts = 0.f;
#pragma unroll
      for (int r = 0; r < 16; ++r){ p0[r] = exp2f(p0[r] - m2); ts += p0[r]; }
      lp += ts;

      // ---- pack P into PV A-fragments (in-register, permlane32_swap) ----
      bf16x8 pa[2];
      {
        union { unsigned u[4]; bf16x8 v; } f0, f1;
        unsigned A0 = cvtpk(p0[0], p0[1]),  B0 = cvtpk(p0[2], p0[3]);
        unsigned A1 = cvtpk(p0[4], p0[5]),  B1 = cvtpk(p0[6], p0[7]);
        plswap(A0, A1); plswap(B0, B1);
        f0.u[0]=A0; f0.u[1]=B0; f0.u[2]=A1; f0.u[3]=B1;  pa[0]=f0.v;
        unsigned A2 = cvtpk(p0[8], p0[9]),  B2 = cvtpk(p0[10], p0[11]);
        unsigned A3 = cvtpk(p0[12], p0[13]),B3 = cvtpk(p0[14], p0[15]);
        plswap(A2, A3); plswap(B2, B3);
        f1.u[0]=A2; f1.u[1]=B2; f1.u[2]=A3; f1.u[3]=B3;  pa[1]=f1.v;
      }

      // ---- PV: O[q][d] += P V, d-tiles 0 (d=ln) and 1 (d=32+ln) ----
      __builtin_amdgcn_s_setprio(1);
#pragma unroll
      for (int st = 0; st < 2; ++st){
        bf16x8 v0 = *(const bf16x8*)&sVb[voff0[st]];
        bf16x8 v1 = *(const bf16x8*)&sVb[voff1[st]];
        yacc0 = __builtin_amdgcn_mfma_f32_32x32x16_bf16(pa[st], v0, yacc0, 0, 0, 0);
        yacc1 = __builtin_amdgcn_mfma_f32_32x32x16_bf16(pa[st], v1, yacc1, 0, 0, 0);
      }
      __builtin_amdgcn_s_setprio(0);
    }
  }

  // ---- epilogue: full row sum, divide, write [token][C] bf16 ----
  float lpf = lp + __shfl_xor(lp, 32);
  float inv = 1.0f / lpf;
#pragma unroll
  for (int r = 0; r < 16; ++r){
    int q = (r&3) + 8*(r>>2) + 4*hi;
    float ir = __shfl(inv, q);               // inv lives at lane q
    int tt = r0 + q;
    size_t rowoff = (size_t)(b*TSEQ + tt)*CMODEL + h*HDIM;
    yb[rowoff + ln]      = f2bf(yacc0[r] * ir);
    yb[rowoff + 32 + ln] = f2bf(yacc1[r] * ir);
  }
}

// ---------------------------------------------------------------------------
// output projection (128x256 tb3), f32 result straight to d_out
// ---------------------------------------------------------------------------
__global__ __launch_bounds__(512, 1) void gemm_proj_kernel(
    const u16* __restrict__ yb, const u16* __restrict__ wpb,
    const float* __restrict__ bp, float* __restrict__ out)
{
  __shared__ u16 sA[3*AREG];
  __shared__ u16 sB[3*BREG];
  const int m0 = blockIdx.y * 128, n0 = blockIdx.x * 256;
  f32x4 acc[4][4];
  gemm_tb3_mainloop(yb, wpb, m0, n0, sA, sB, acc);

  const int tid = threadIdx.x, w = tid >> 6, lane = tid & 63;
  const int ln = lane & 15, g = lane >> 4;
  const int wm = w >> 2, wn = w & 3;
#pragma unroll
  for (int mt = 0; mt < 4; ++mt)
#pragma unroll
    for (int nt = 0; nt < 4; ++nt){
      int o = n0 + wn*64 + nt*16 + ln;
      float bb = bp[o];
#pragma unroll
      for (int rr = 0; rr < 4; ++rr){
        int t = m0 + wm*64 + mt*16 + g*4 + rr;
        out[(size_t)t*CMODEL + o] = acc[mt][nt][rr] + bb;
      }
    }
}

// ---------------------------------------------------------------------------
extern "C" void kernel_launch(void* const* d_in, const int* in_sizes, int n_in,
                              void* d_out, int out_size, void* d_ws, size_t ws_size,
                              hipStream_t stream)
{
  const float* x  = (const float*)d_in[0];
  const float* wq = (const float*)d_in[1];
  const float* bq = (const float*)d_in[2];
  const float* wk = (const float*)d_in[3];
  const float* bk = (const float*)d_in[4];
  const float* wv = (const float*)d_in[5];
  const float* bv = (const float*)d_in[6];
  const float* wp = (const float*)d_in[7];
  const float* bp = (const float*)d_in[8];

  char* ws = (char*)d_ws;
  u16*    xb   = (u16*)   (ws + 0);           // 16 MiB
  u16*    wqb  = (u16*)   (ws + 16777216);    // 2 MiB
  u16*    wkb  = (u16*)   (ws + 18874368);
  u16*    wvb  = (u16*)   (ws + 20971520);
  u16*    wpb  = (u16*)   (ws + 23068672);
  float2* rope = (float2*)(ws + 25165824);    // 512 KiB
  u16*    Qh   = (u16*)   (ws + 25690112);    // 16 MiB  [bh][t][d]
  u16*    Kh   = (u16*)   (ws + 42467328);    // 16 MiB  [bh][t][d]
  u16*    Vt   = (u16*)   (ws + 59244544);    // 16 MiB  [bh][d][t]
  u16*    yb   = (u16*)   (ws + 76021760);    // 16 MiB  [token][C]

  cast_bf16_kernel<<<2048, 256, 0, stream>>>(x,  xb,  MTOK*CMODEL/4);
  cast4_bf16_kernel<<<dim3(256, 4), 256, 0, stream>>>(wq, wk, wv, wp, wqb, wkb, wvb, wpb,
                                                      CMODEL*CMODEL/4);
  rope_table_kernel<<<(TSEQ*(HDIM/2) + 255)/256, 256, 0, stream>>>(rope);

  gemm_qkv_kernel<<<dim3(CMODEL/256, MTOK/128, 3), 512, 0, stream>>>(
      xb, wqb, wkb, wvb, bq, bk, bv, rope, Qh, Kh, Vt);

  attn_kernel<<<dim3(2048), 128, 0, stream>>>(Qh, Kh, Vt, yb);

  gemm_proj_kernel<<<dim3(CMODEL/256, MTOK/128), 512, 0, stream>>>(yb, wpb, bp, (float*)d_out);
}

// Round 15
// 199.800 us; speedup vs baseline: 1.0849x; 1.0849x over previous
//
#include <hip/hip_runtime.h>

typedef __attribute__((ext_vector_type(8))) __bf16 bf16x8;
typedef __attribute__((ext_vector_type(4))) float f32x4;
typedef __attribute__((ext_vector_type(16))) float f32x16;
typedef unsigned short u16;

// Problem constants
#define TSEQ   2048
#define NB     4
#define NHEAD  16
#define HDIM   64
#define CMODEL 1024
#define MTOK   (NB*TSEQ)          // 8192 tokens

__device__ __forceinline__ u16 f2bf(float x){
  unsigned u = __float_as_uint(x);
  u += 0x7fffu + ((u >> 16) & 1u);          // RNE (no NaN inputs here)
  return (u16)(u >> 16);
}

// pack 2 f32 -> u32 of 2 bf16 (lo in low 16), RNE
__device__ __forceinline__ unsigned cvtpk(float lo, float hi){
  unsigned r;
  asm("v_cvt_pk_bf16_f32 %0, %1, %2" : "=v"(r) : "v"(lo), "v"(hi));
  return r;
}
// v_permlane32_swap: a.lanes[32:63] <-> b.lanes[0:31]
__device__ __forceinline__ void plswap(unsigned &a, unsigned &b){
  asm volatile("v_permlane32_swap_b32 %0, %1" : "+v"(a), "+v"(b));
}

// async global->LDS, 16B per lane. lds_base must be wave-uniform (affine in
// lane with 16B slope); HW writes lane i at base + i*16.
__device__ __forceinline__ void async16(const void* g, const u16* lds_base){
  __builtin_amdgcn_global_load_lds(
      (const __attribute__((address_space(1))) unsigned*)(uintptr_t)g,
      (__attribute__((address_space(3))) unsigned*)(unsigned)(uintptr_t)lds_base,
      16, 0, 0);
}

// ---------------------------------------------------------------------------
// prep kernels
// ---------------------------------------------------------------------------
__global__ void cast_bf16_kernel(const float* __restrict__ src, u16* __restrict__ dst, int n4){
  int i = blockIdx.x * blockDim.x + threadIdx.x;
  int stride = gridDim.x * blockDim.x;
  for (; i < n4; i += stride){
    float4 v = ((const float4*)src)[i];
    ((ushort4*)dst)[i] = make_ushort4(f2bf(v.x), f2bf(v.y), f2bf(v.z), f2bf(v.w));
  }
}

__global__ void cast4_bf16_kernel(const float* __restrict__ s0, const float* __restrict__ s1,
                                  const float* __restrict__ s2, const float* __restrict__ s3,
                                  u16* __restrict__ d0, u16* __restrict__ d1,
                                  u16* __restrict__ d2, u16* __restrict__ d3, int n4){
  int which = blockIdx.y;
  const float* s = (which==0)?s0:(which==1)?s1:(which==2)?s2:s3;
  u16* d        = (which==0)?d0:(which==1)?d1:(which==2)?d2:d3;
  int i = blockIdx.x * blockDim.x + threadIdx.x;
  int stride = gridDim.x * blockDim.x;
  for (; i < n4; i += stride){
    float4 v = ((const float4*)s)[i];
    ((ushort4*)d)[i] = make_ushort4(f2bf(v.x), f2bf(v.y), f2bf(v.z), f2bf(v.w));
  }
}

__global__ void rope_table_kernel(float2* __restrict__ rope){
  int i = blockIdx.x * blockDim.x + threadIdx.x;       // T * HDIM/2 = 2048*32
  if (i >= TSEQ * (HDIM/2)) return;
  int t = i >> 5, j = i & 31;
  float theta = exp2f(-(float)j * (13.287712379549449f / 32.f));
  float ang = (float)t * theta;
  rope[i] = make_float2(cosf(ang), sinf(ang));
}

// ---------------------------------------------------------------------------
// 128x256 tile GEMM, triple-buffered BK=64, counted vmcnt pipeline (verified).
// ---------------------------------------------------------------------------
#define AREG 8192    // u16 per A buf (128*64)
#define BREG 16384   // u16 per B buf (256*64)

__device__ __forceinline__ void gemm_tb3_mainloop(
    const u16* __restrict__ A, const u16* __restrict__ B,
    int m0, int n0, u16* sAb, u16* sBb, f32x4 acc[4][4])
{
  const int tid = threadIdx.x;
  const int lane = tid & 63, w = tid >> 6;
  const int ln = lane & 15, g = lane >> 4;
  const int wm = w >> 2, wn = w & 3;

  const f32x4 zero = {0.f, 0.f, 0.f, 0.f};
#pragma unroll
  for (int i = 0; i < 4; ++i)
#pragma unroll
    for (int nt = 0; nt < 4; ++nt) acc[i][nt] = zero;

  const int cA0 = tid,       rA0 = cA0 >> 3;
  const int cA1 = 512 + tid, rA1 = cA1 >> 3;
  const u16* aS0 = A + (size_t)(m0 + rA0)*CMODEL + (((cA0 & 7) ^ (rA0 & 7)) << 3);
  const u16* aS1 = A + (size_t)(m0 + rA1)*CMODEL + (((cA1 & 7) ^ (rA1 & 7)) << 3);
  const unsigned dA0 = (unsigned)cA0 * 8, dA1 = (unsigned)cA1 * 8;
  const u16* bS[4]; unsigned dB[4];
#pragma unroll
  for (int j = 0; j < 4; ++j){
    int c = j*512 + tid, r = c >> 3;
    bS[j] = B + (size_t)(n0 + r)*CMODEL + (((c & 7) ^ (r & 7)) << 3);
    dB[j] = (unsigned)c * 8;
  }

  unsigned aoff[4][2], boff[4][2];
#pragma unroll
  for (int i = 0; i < 4; ++i){
    int r = wm*64 + i*16 + ln;
#pragma unroll
    for (int kk = 0; kk < 2; ++kk)
      aoff[i][kk] = (unsigned)(r*8 + ((kk*4 + g) ^ (r & 7))) * 8;
  }
#pragma unroll
  for (int nt = 0; nt < 4; ++nt){
    int r = wn*64 + nt*16 + ln;
#pragma unroll
    for (int kk = 0; kk < 2; ++kk)
      boff[nt][kk] = (unsigned)(r*8 + ((kk*4 + g) ^ (r & 7))) * 8;
  }

  async16(aS0,       sAb + dA0);
  async16(aS1,       sAb + dA1);
  async16(bS[0],     sBb + dB[0]);
  async16(bS[1],     sBb + dB[1]);
  async16(bS[2],     sBb + dB[2]);
  async16(bS[3],     sBb + dB[3]);
  async16(aS0 + 64,  sAb + AREG + dA0);
  async16(aS1 + 64,  sAb + AREG + dA1);
  async16(bS[0] + 64, sBb + BREG + dB[0]);
  async16(bS[1] + 64, sBb + BREG + dB[1]);
  async16(bS[2] + 64, sBb + BREG + dB[2]);
  async16(bS[3] + 64, sBb + BREG + dB[3]);
  asm volatile("s_waitcnt vmcnt(6)" ::: "memory");
  asm volatile("s_barrier" ::: "memory");

#pragma unroll 1
  for (int kt = 0; kt < 16; ++kt){
    const int cb = kt % 3;
    const int nb = (kt + 2) % 3;
    const u16* Ab = sAb + cb*AREG;
    const u16* Bb = sBb + cb*BREG;
    u16* An = sAb + nb*AREG;
    u16* Bn = sBb + nb*BREG;
    const unsigned ko = (unsigned)(kt + 2) * 64u;
    const bool st = (kt < 14);

    bf16x8 a0, a1, a2, a3, b0, b1, b2, b3;

    a0 = *(const bf16x8*)&Ab[aoff[0][0]];
    a1 = *(const bf16x8*)&Ab[aoff[1][0]];
    b0 = *(const bf16x8*)&Bb[boff[0][0]];
    b1 = *(const bf16x8*)&Bb[boff[1][0]];
    b2 = *(const bf16x8*)&Bb[boff[2][0]];
    b3 = *(const bf16x8*)&Bb[boff[3][0]];
    if (st){ async16(aS0 + ko, An + dA0); async16(aS1 + ko, An + dA1); }
    asm volatile("s_barrier" ::: "memory");
    __builtin_amdgcn_s_setprio(1);
    acc[0][0] = __builtin_amdgcn_mfma_f32_16x16x32_bf16(a0, b0, acc[0][0], 0,0,0);
    acc[0][1] = __builtin_amdgcn_mfma_f32_16x16x32_bf16(a0, b1, acc[0][1], 0,0,0);
    acc[0][2] = __builtin_amdgcn_mfma_f32_16x16x32_bf16(a0, b2, acc[0][2], 0,0,0);
    acc[0][3] = __builtin_amdgcn_mfma_f32_16x16x32_bf16(a0, b3, acc[0][3], 0,0,0);
    acc[1][0] = __builtin_amdgcn_mfma_f32_16x16x32_bf16(a1, b0, acc[1][0], 0,0,0);
    acc[1][1] = __builtin_amdgcn_mfma_f32_16x16x32_bf16(a1, b1, acc[1][1], 0,0,0);
    acc[1][2] = __builtin_amdgcn_mfma_f32_16x16x32_bf16(a1, b2, acc[1][2], 0,0,0);
    acc[1][3] = __builtin_amdgcn_mfma_f32_16x16x32_bf16(a1, b3, acc[1][3], 0,0,0);
    __builtin_amdgcn_s_setprio(0);
    asm volatile("s_barrier" ::: "memory");

    a2 = *(const bf16x8*)&Ab[aoff[2][0]];
    a3 = *(const bf16x8*)&Ab[aoff[3][0]];
    if (st){ async16(bS[0] + ko, Bn + dB[0]); async16(bS[1] + ko, Bn + dB[1]); }
    asm volatile("s_barrier" ::: "memory");
    __builtin_amdgcn_s_setprio(1);
    acc[2][0] = __builtin_amdgcn_mfma_f32_16x16x32_bf16(a2, b0, acc[2][0], 0,0,0);
    acc[2][1] = __builtin_amdgcn_mfma_f32_16x16x32_bf16(a2, b1, acc[2][1], 0,0,0);
    acc[2][2] = __builtin_amdgcn_mfma_f32_16x16x32_bf16(a2, b2, acc[2][2], 0,0,0);
    acc[2][3] = __builtin_amdgcn_mfma_f32_16x16x32_bf16(a2, b3, acc[2][3], 0,0,0);
    acc[3][0] = __builtin_amdgcn_mfma_f32_16x16x32_bf16(a3, b0, acc[3][0], 0,0,0);
    acc[3][1] = __builtin_amdgcn_mfma_f32_16x16x32_bf16(a3, b1, acc[3][1], 0,0,0);
    acc[3][2] = __builtin_amdgcn_mfma_f32_16x16x32_bf16(a3, b2, acc[3][2], 0,0,0);
    acc[3][3] = __builtin_amdgcn_mfma_f32_16x16x32_bf16(a3, b3, acc[3][3], 0,0,0);
    __builtin_amdgcn_s_setprio(0);
    asm volatile("s_barrier" ::: "memory");

    a0 = *(const bf16x8*)&Ab[aoff[0][1]];
    a1 = *(const bf16x8*)&Ab[aoff[1][1]];
    b0 = *(const bf16x8*)&Bb[boff[0][1]];
    b1 = *(const bf16x8*)&Bb[boff[1][1]];
    b2 = *(const bf16x8*)&Bb[boff[2][1]];
    b3 = *(const bf16x8*)&Bb[boff[3][1]];
    if (st) async16(bS[2] + ko, Bn + dB[2]);
    asm volatile("s_barrier" ::: "memory");
    __builtin_amdgcn_s_setprio(1);
    acc[0][0] = __builtin_amdgcn_mfma_f32_16x16x32_bf16(a0, b0, acc[0][0], 0,0,0);
    acc[0][1] = __builtin_amdgcn_mfma_f32_16x16x32_bf16(a0, b1, acc[0][1], 0,0,0);
    acc[0][2] = __builtin_amdgcn_mfma_f32_16x16x32_bf16(a0, b2, acc[0][2], 0,0,0);
    acc[0][3] = __builtin_amdgcn_mfma_f32_16x16x32_bf16(a0, b3, acc[0][3], 0,0,0);
    acc[1][0] = __builtin_amdgcn_mfma_f32_16x16x32_bf16(a1, b0, acc[1][0], 0,0,0);
    acc[1][1] = __builtin_amdgcn_mfma_f32_16x16x32_bf16(a1, b1, acc[1][1], 0,0,0);
    acc[1][2] = __builtin_amdgcn_mfma_f32_16x16x32_bf16(a1, b2, acc[1][2], 0,0,0);
    acc[1][3] = __builtin_amdgcn_mfma_f32_16x16x32_bf16(a1, b3, acc[1][3], 0,0,0);
    __builtin_amdgcn_s_setprio(0);
    asm volatile("s_barrier" ::: "memory");

    a2 = *(const bf16x8*)&Ab[aoff[2][1]];
    a3 = *(const bf16x8*)&Ab[aoff[3][1]];
    if (st) async16(bS[3] + ko, Bn + dB[3]);
    asm volatile("s_barrier" ::: "memory");
    __builtin_amdgcn_s_setprio(1);
    acc[2][0] = __builtin_amdgcn_mfma_f32_16x16x32_bf16(a2, b0, acc[2][0], 0,0,0);
    acc[2][1] = __builtin_amdgcn_mfma_f32_16x16x32_bf16(a2, b1, acc[2][1], 0,0,0);
    acc[2][2] = __builtin_amdgcn_mfma_f32_16x16x32_bf16(a2, b2, acc[2][2], 0,0,0);
    acc[2][3] = __builtin_amdgcn_mfma_f32_16x16x32_bf16(a2, b3, acc[2][3], 0,0,0);
    acc[3][0] = __builtin_amdgcn_mfma_f32_16x16x32_bf16(a3, b0, acc[3][0], 0,0,0);
    acc[3][1] = __builtin_amdgcn_mfma_f32_16x16x32_bf16(a3, b1, acc[3][1], 0,0,0);
    acc[3][2] = __builtin_amdgcn_mfma_f32_16x16x32_bf16(a3, b2, acc[3][2], 0,0,0);
    acc[3][3] = __builtin_amdgcn_mfma_f32_16x16x32_bf16(a3, b3, acc[3][3], 0,0,0);
    __builtin_amdgcn_s_setprio(0);
    if (st) asm volatile("s_waitcnt vmcnt(6)" ::: "memory");
    else    asm volatile("s_waitcnt vmcnt(0)" ::: "memory");
    asm volatile("s_barrier" ::: "memory");
  }
}

// ---------------------------------------------------------------------------
// QKV projection (128x256 tb3) + bias + RoPE(Q,K) + head-split; V transposed.
// ---------------------------------------------------------------------------
#define SCQ 0.18033688011112042f   // 0.125 * log2(e)

__global__ __launch_bounds__(512, 1) void gemm_qkv_kernel(
    const u16* __restrict__ xb,
    const u16* __restrict__ wqb, const u16* __restrict__ wkb, const u16* __restrict__ wvb,
    const float* __restrict__ bq, const float* __restrict__ bk, const float* __restrict__ bv,
    const float2* __restrict__ rope,
    u16* __restrict__ Qh, u16* __restrict__ Kh, u16* __restrict__ Vt)
{
  __shared__ u16 sA[3*AREG];
  __shared__ u16 sB[3*BREG];
  const int z = blockIdx.z;
  const u16*  W    = (z == 0) ? wqb : (z == 1) ? wkb : wvb;
  const float* bias = (z == 0) ? bq  : (z == 1) ? bk  : bv;
  const int m0 = blockIdx.y * 128, n0 = blockIdx.x * 256;

  f32x4 acc[4][4];
  gemm_tb3_mainloop(xb, W, m0, n0, sA, sB, acc);

  const int tid = threadIdx.x, w = tid >> 6, lane = tid & 63;
  const int ln = lane & 15, g = lane >> 4;
  const int wm = w >> 2, wn = w & 3;

#pragma unroll
  for (int mt = 0; mt < 4; ++mt){
#pragma unroll
    for (int nt = 0; nt < 4; ++nt){
      int o  = n0 + wn*64 + nt*16 + ln;    // output feature 0..1023
      float bb = bias[o];
      int h  = o >> 6;
      int dd = o & 63;
      if (z < 2){
        int j = dd >> 1;
        u16* dst = (z == 0) ? Qh : Kh;
        float qs = (z == 0) ? SCQ : 1.0f;
#pragma unroll
        for (int rr = 0; rr < 4; ++rr){
          int t  = m0 + wm*64 + mt*16 + g*4 + rr;   // global token
          int b  = t >> 11, tt = t & (TSEQ-1);
          float v  = acc[mt][nt][rr] + bb;
          float pv = __shfl_xor(v, 1);              // rope partner (o^1), same row
          float2 cs = rope[tt*32 + j];
          float out = ((o & 1) == 0) ? (v*cs.x - pv*cs.y) : (pv*cs.y + v*cs.x);
          dst[(size_t)((b*NHEAD + h)*TSEQ + tt)*HDIM + dd] = f2bf(out * qs);
        }
      } else {
        int t0 = m0 + wm*64 + mt*16 + g*4;
        int b  = t0 >> 11, tt0 = t0 & (TSEQ-1);
        u16 pk[4];
#pragma unroll
        for (int rr = 0; rr < 4; ++rr) pk[rr] = f2bf(acc[mt][nt][rr] + bb);
        *(ushort4*)&Vt[(size_t)((b*NHEAD + h)*HDIM + dd)*TSEQ + tt0] =
            make_ushort4(pk[0], pk[1], pk[2], pk[3]);
      }
    }
  }
}

// ---------------------------------------------------------------------------
// Flash attention v13 — m214-style 8-wave blocks, paired supertiles.
//  - 512 thr = 8 waves x 32 q-rows = 256-row supertile; block does supertiles
//    (7-p) then (p) -> uniform 36 kv-tile steps; grid 256 = 1 block/CU.
//  - KVBLK=64; K,V triple-buffered (48KB), counted vmcnt (tb3 ledger:
//    2 loads/thread/tile; vmcnt(2) when 2-ahead staged, else vmcnt(0)).
//  - per-wave math = v8 (verified): swapped 32x32 MFMA p0/p1, in-register
//    softmax, defer-max, cvt_pk+permlane pack; diag jtw = 4s + (w>>1),
//    wodd = w&1 (masked half skipped via full1).
// ---------------------------------------------------------------------------
__global__ __launch_bounds__(512, 1) void attn_kernel(
    const u16* __restrict__ Qh, const u16* __restrict__ Kh,
    const u16* __restrict__ Vt, u16* __restrict__ yb)
{
  __shared__ u16 sK[3][64*64];
  __shared__ u16 sV[3][64*64];

  const int tid = threadIdx.x, w = tid >> 6, lane = tid & 63;
  const int ln = lane & 31, hi = lane >> 5;

  const int bid = blockIdx.x;          // 0..255
  const int bh  = bid >> 2;            // 0..63
  const int pr  = bid & 3;             // pair index 0..3
  const int b   = bh >> 4, h = bh & (NHEAD-1);

  const u16* Qbase = Qh + (size_t)bh * TSEQ * HDIM;
  const u16* Kbase = Kh + (size_t)bh * TSEQ * HDIM;
  const u16* Vbase = Vt + (size_t)bh * HDIM * TSEQ;

  // staging: thread stages chunk tid of K tile and of V tile (8KB each)
  const int cr = tid >> 3, cs = tid & 7;
  const u16* kp = Kbase + (size_t)cr*HDIM + ((cs ^ (cr&7))<<3);
  const u16* vp = Vbase + (size_t)cr*TSEQ + ((cs ^ (cr&7))<<3);
  const unsigned dstw = (unsigned)(w*64)*8;     // wave-uniform LDS base (u16)

  // frag read offsets (u16 units), rows are 64-u16 wide
  const int swz = ln & 7;
  unsigned offd[4];
#pragma unroll
  for (int d = 0; d < 4; ++d) offd[d] = ((unsigned)((2*d + hi) ^ swz)) * 8;
  const unsigned rowl = (unsigned)ln * 64;
  const unsigned rowh = rowl + 32*64;

  const f32x16 zero16 = {0,0,0,0,0,0,0,0,0,0,0,0,0,0,0,0};
  const int wodd = w & 1;

#pragma unroll 1
  for (int ss = 0; ss < 2; ++ss){
    const int s   = ss ? pr : (7 - pr);        // big supertile first
    const int r0  = s*256 + w*32;              // wave's first q-row
    const int jtb = 4*s + 3;                   // supertile's last kv-tile
    const int jtw = 4*s + (w >> 1);            // wave's diagonal kv-tile
    const size_t kvoff = 0;                    // kv tiles are absolute 0..jtb

    // Q fragments
    bf16x8 qf[4];
#pragma unroll
    for (int ds = 0; ds < 4; ++ds)
      qf[ds] = *(const bf16x8*)&Qbase[(size_t)(r0 + ln)*HDIM + ds*16 + hi*8];

    f32x16 yacc0 = zero16, yacc1 = zero16;
    float m2 = -1e30f, lp = 0.f;

    // prologue: stage tiles 0,1 -> bufs 0,1  (jtb >= 3 always)
    async16(kp,                       sK[0] + dstw);
    async16(vp,                       sV[0] + dstw);
    async16(kp + (size_t)64*HDIM,     sK[1] + dstw);
    async16(vp + 64,                  sV[1] + dstw);
    asm volatile("s_waitcnt vmcnt(2)" ::: "memory");
    asm volatile("s_barrier" ::: "memory");

#pragma unroll 1
    for (int jt = 0; jt <= jtb; ++jt){
      // stage jt+2 into buf (jt+2)%3
      const bool st2 = (jt + 2 <= jtb);
      if (st2){
        const int nb = (jt + 2) % 3;
        async16(kp + (size_t)(jt+2)*64*HDIM, sK[nb] + dstw);
        async16(vp + (size_t)(jt+2)*64,      sV[nb] + dstw);
      }

      if (jt <= jtw){
        const int cb = jt % 3;
        const u16* sKb = sK[cb];
        const u16* sVb = sV[cb];
        const bool full1 = (jt < jtw) || wodd;

        // ---- QK^T (swapped): p0 = kv rows 0..31, p1 = 32..63 ----
        f32x16 p0 = zero16, p1 = zero16;
        __builtin_amdgcn_s_setprio(1);
#pragma unroll
        for (int ds = 0; ds < 4; ++ds){
          bf16x8 k0 = *(const bf16x8*)&sKb[rowl + offd[ds]];
          p0 = __builtin_amdgcn_mfma_f32_32x32x16_bf16(k0, qf[ds], p0, 0, 0, 0);
        }
        if (full1){
#pragma unroll
          for (int ds = 0; ds < 4; ++ds){
            bf16x8 k1 = *(const bf16x8*)&sKb[rowh + offd[ds]];
            p1 = __builtin_amdgcn_mfma_f32_32x32x16_bf16(k1, qf[ds], p1, 0, 0, 0);
          }
        }
        __builtin_amdgcn_s_setprio(0);

        // ---- causal mask on the wave's diag tile ----
        if (jt == jtw){
#pragma unroll
          for (int r = 0; r < 16; ++r){
            int k0r = (r&3) + 8*(r>>2) + 4*hi;
            bool cut = k0r > ln;
            if (!wodd){ if (cut) p0[r] = -1e30f; }
            else      { if (cut) p1[r] = -1e30f; }
          }
        }

        // ---- lane-local row max ----
        float lm = p0[0];
#pragma unroll
        for (int r = 1; r < 16; ++r) lm = fmaxf(lm, p0[r]);
        if (full1){
#pragma unroll
          for (int r = 0; r < 16; ++r) lm = fmaxf(lm, p1[r]);
        }

        // defer-max
        if (__any(lm - m2 > 8.0f)){
          float lmp = __shfl_xor(lm, 32);
          float mn  = fmaxf(m2, fmaxf(lm, lmp));
          float scl = exp2f(m2 - mn);
          m2 = mn;
          lp *= scl;
#pragma unroll
          for (int r = 0; r < 16; ++r){
            float sr = __shfl(scl, (r&3) + 8*(r>>2) + 4*hi);
            yacc0[r] *= sr; yacc1[r] *= sr;
          }
        }

        // ---- exp + per-lane partial sum ----
        float ts = 0.f;
#pragma unroll
        for (int r = 0; r < 16; ++r){ p0[r] = exp2f(p0[r] - m2); ts += p0[r]; }
        if (full1){
#pragma unroll
          for (int r = 0; r < 16; ++r){ p1[r] = exp2f(p1[r] - m2); ts += p1[r]; }
        }
        lp += ts;

        // ---- pack P into PV A-fragments ----
        bf16x8 pa[4];
        {
          union { unsigned u[4]; bf16x8 v; } f0, f1;
          unsigned A0 = cvtpk(p0[0], p0[1]),  B0 = cvtpk(p0[2], p0[3]);
          unsigned A1 = cvtpk(p0[4], p0[5]),  B1 = cvtpk(p0[6], p0[7]);
          plswap(A0, A1); plswap(B0, B1);
          f0.u[0]=A0; f0.u[1]=B0; f0.u[2]=A1; f0.u[3]=B1;  pa[0]=f0.v;
          unsigned A2 = cvtpk(p0[8], p0[9]),  B2 = cvtpk(p0[10], p0[11]);
          unsigned A3 = cvtpk(p0[12], p0[13]),B3 = cvtpk(p0[14], p0[15]);
          plswap(A2, A3); plswap(B2, B3);
          f1.u[0]=A2; f1.u[1]=B2; f1.u[2]=A3; f1.u[3]=B3;  pa[1]=f1.v;
        }
        if (full1){
          union { unsigned u[4]; bf16x8 v; } f2, f3;
          unsigned A4 = cvtpk(p1[0], p1[1]),  B4 = cvtpk(p1[2], p1[3]);
          unsigned A5 = cvtpk(p1[4], p1[5]),  B5 = cvtpk(p1[6], p1[7]);
          plswap(A4, A5); plswap(B4, B5);
          f2.u[0]=A4; f2.u[1]=B4; f2.u[2]=A5; f2.u[3]=B5;  pa[2]=f2.v;
          unsigned A6 = cvtpk(p1[8], p1[9]),  B6 = cvtpk(p1[10], p1[11]);
          unsigned A7 = cvtpk(p1[12], p1[13]),B7 = cvtpk(p1[14], p1[15]);
          plswap(A6, A7); plswap(B6, B7);
          f3.u[0]=A6; f3.u[1]=B6; f3.u[2]=A7; f3.u[3]=B7;  pa[3]=f3.v;
        }

        // ---- PV ----
        __builtin_amdgcn_s_setprio(1);
#pragma unroll
        for (int st = 0; st < 2; ++st){
          bf16x8 v0 = *(const bf16x8*)&sVb[rowl + offd[st]];
          bf16x8 v1 = *(const bf16x8*)&sVb[rowh + offd[st]];
          yacc0 = __builtin_amdgcn_mfma_f32_32x32x16_bf16(pa[st], v0, yacc0, 0, 0, 0);
          yacc1 = __builtin_amdgcn_mfma_f32_32x32x16_bf16(pa[st], v1, yacc1, 0, 0, 0);
        }
        if (full1){
#pragma unroll
          for (int st = 2; st < 4; ++st){
            bf16x8 v0 = *(const bf16x8*)&sVb[rowl + offd[st]];
            bf16x8 v1 = *(const bf16x8*)&sVb[rowh + offd[st]];
            yacc0 = __builtin_amdgcn_mfma_f32_32x32x16_bf16(pa[st], v0, yacc0, 0, 0, 0);
            yacc1 = __builtin_amdgcn_mfma_f32_32x32x16_bf16(pa[st], v1, yacc1, 0, 0, 0);
          }
        }
        __builtin_amdgcn_s_setprio(0);
      }

      // ledger: ensure stage(jt+1) landed before next iter; never 0 until tail
      if (st2) asm volatile("s_waitcnt vmcnt(2)" ::: "memory");
      else     asm volatile("s_waitcnt vmcnt(0)" ::: "memory");
      asm volatile("s_barrier" ::: "memory");
      (void)kvoff;
    }

    // ---- epilogue: full row sum, divide, write [token][C] bf16 ----
    float lpf = lp + __shfl_xor(lp, 32);
    float inv = 1.0f / lpf;
#pragma unroll
    for (int r = 0; r < 16; ++r){
      int q = (r&3) + 8*(r>>2) + 4*hi;
      float ir = __shfl(inv, q);
      int tt = r0 + q;
      size_t rowoff = (size_t)(b*TSEQ + tt)*CMODEL + h*HDIM;
      yb[rowoff + ln]      = f2bf(yacc0[r] * ir);
      yb[rowoff + 32 + ln] = f2bf(yacc1[r] * ir);
    }
    asm volatile("s_barrier" ::: "memory");   // all waves done before next supertile re-stage
  }
}

// ---------------------------------------------------------------------------
// output projection (128x256 tb3), f32 result straight to d_out
// ---------------------------------------------------------------------------
__global__ __launch_bounds__(512, 1) void gemm_proj_kernel(
    const u16* __restrict__ yb, const u16* __restrict__ wpb,
    const float* __restrict__ bp, float* __restrict__ out)
{
  __shared__ u16 sA[3*AREG];
  __shared__ u16 sB[3*BREG];
  const int m0 = blockIdx.y * 128, n0 = blockIdx.x * 256;
  f32x4 acc[4][4];
  gemm_tb3_mainloop(yb, wpb, m0, n0, sA, sB, acc);

  const int tid = threadIdx.x, w = tid >> 6, lane = tid & 63;
  const int ln = lane & 15, g = lane >> 4;
  const int wm = w >> 2, wn = w & 3;
#pragma unroll
  for (int mt = 0; mt < 4; ++mt)
#pragma unroll
    for (int nt = 0; nt < 4; ++nt){
      int o = n0 + wn*64 + nt*16 + ln;
      float bb = bp[o];
#pragma unroll
      for (int rr = 0; rr < 4; ++rr){
        int t = m0 + wm*64 + mt*16 + g*4 + rr;
        out[(size_t)t*CMODEL + o] = acc[mt][nt][rr] + bb;
      }
    }
}

// ---------------------------------------------------------------------------
extern "C" void kernel_launch(void* const* d_in, const int* in_sizes, int n_in,
                              void* d_out, int out_size, void* d_ws, size_t ws_size,
                              hipStream_t stream)
{
  const float* x  = (const float*)d_in[0];
  const float* wq = (const float*)d_in[1];
  const float* bq = (const float*)d_in[2];
  const float* wk = (const float*)d_in[3];
  const float* bk = (const float*)d_in[4];
  const float* wv = (const float*)d_in[5];
  const float* bv = (const float*)d_in[6];
  const float* wp = (const float*)d_in[7];
  const float* bp = (const float*)d_in[8];

  char* ws = (char*)d_ws;
  u16*    xb   = (u16*)   (ws + 0);           // 16 MiB
  u16*    wqb  = (u16*)   (ws + 16777216);    // 2 MiB
  u16*    wkb  = (u16*)   (ws + 18874368);
  u16*    wvb  = (u16*)   (ws + 20971520);
  u16*    wpb  = (u16*)   (ws + 23068672);
  float2* rope = (float2*)(ws + 25165824);    // 512 KiB
  u16*    Qh   = (u16*)   (ws + 25690112);    // 16 MiB  [bh][t][d]
  u16*    Kh   = (u16*)   (ws + 42467328);    // 16 MiB  [bh][t][d]
  u16*    Vt   = (u16*)   (ws + 59244544);    // 16 MiB  [bh][d][t]
  u16*    yb   = (u16*)   (ws + 76021760);    // 16 MiB  [token][C]

  cast_bf16_kernel<<<2048, 256, 0, stream>>>(x,  xb,  MTOK*CMODEL/4);
  cast4_bf16_kernel<<<dim3(256, 4), 256, 0, stream>>>(wq, wk, wv, wp, wqb, wkb, wvb, wpb,
                                                      CMODEL*CMODEL/4);
  rope_table_kernel<<<(TSEQ*(HDIM/2) + 255)/256, 256, 0, stream>>>(rope);

  gemm_qkv_kernel<<<dim3(CMODEL/256, MTOK/128, 3), 512, 0, stream>>>(
      xb, wqb, wkb, wvb, bq, bk, bv, rope, Qh, Kh, Vt);

  attn_kernel<<<dim3(256), 512, 0, stream>>>(Qh, Kh, Vt, yb);

  gemm_proj_kernel<<<dim3(CMODEL/256, MTOK/128), 512, 0, stream>>>(yb, wpb, bp, (float*)d_out);
}

// Round 16
// 198.998 us; speedup vs baseline: 1.0893x; 1.0040x over previous
//
#include <hip/hip_runtime.h>

typedef __attribute__((ext_vector_type(8))) __bf16 bf16x8;
typedef __attribute__((ext_vector_type(4))) float f32x4;
typedef __attribute__((ext_vector_type(16))) float f32x16;
typedef unsigned short u16;

// Problem constants
#define TSEQ   2048
#define NB     4
#define NHEAD  16
#define HDIM   64
#define CMODEL 1024
#define MTOK   (NB*TSEQ)          // 8192 tokens

__device__ __forceinline__ u16 f2bf(float x){
  unsigned u = __float_as_uint(x);
  u += 0x7fffu + ((u >> 16) & 1u);          // RNE (no NaN inputs here)
  return (u16)(u >> 16);
}

// pack 2 f32 -> u32 of 2 bf16 (lo in low 16), RNE
__device__ __forceinline__ unsigned cvtpk(float lo, float hi){
  unsigned r;
  asm("v_cvt_pk_bf16_f32 %0, %1, %2" : "=v"(r) : "v"(lo), "v"(hi));
  return r;
}
// v_permlane32_swap: a.lanes[32:63] <-> b.lanes[0:31]
__device__ __forceinline__ void plswap(unsigned &a, unsigned &b){
  asm volatile("v_permlane32_swap_b32 %0, %1" : "+v"(a), "+v"(b));
}

// async global->LDS, 16B per lane. lds_base must be wave-uniform (affine in
// lane with 16B slope); HW writes lane i at base + i*16.
__device__ __forceinline__ void async16(const void* g, const u16* lds_base){
  __builtin_amdgcn_global_load_lds(
      (const __attribute__((address_space(1))) unsigned*)(uintptr_t)g,
      (__attribute__((address_space(3))) unsigned*)(unsigned)(uintptr_t)lds_base,
      16, 0, 0);
}

// ---------------------------------------------------------------------------
// prep kernels
// ---------------------------------------------------------------------------
__global__ void cast_bf16_kernel(const float* __restrict__ src, u16* __restrict__ dst, int n4){
  int i = blockIdx.x * blockDim.x + threadIdx.x;
  int stride = gridDim.x * blockDim.x;
  for (; i < n4; i += stride){
    float4 v = ((const float4*)src)[i];
    ((ushort4*)dst)[i] = make_ushort4(f2bf(v.x), f2bf(v.y), f2bf(v.z), f2bf(v.w));
  }
}

__global__ void cast4_bf16_kernel(const float* __restrict__ s0, const float* __restrict__ s1,
                                  const float* __restrict__ s2, const float* __restrict__ s3,
                                  u16* __restrict__ d0, u16* __restrict__ d1,
                                  u16* __restrict__ d2, u16* __restrict__ d3, int n4){
  int which = blockIdx.y;
  const float* s = (which==0)?s0:(which==1)?s1:(which==2)?s2:s3;
  u16* d        = (which==0)?d0:(which==1)?d1:(which==2)?d2:d3;
  int i = blockIdx.x * blockDim.x + threadIdx.x;
  int stride = gridDim.x * blockDim.x;
  for (; i < n4; i += stride){
    float4 v = ((const float4*)s)[i];
    ((ushort4*)d)[i] = make_ushort4(f2bf(v.x), f2bf(v.y), f2bf(v.z), f2bf(v.w));
  }
}

__global__ void rope_table_kernel(float2* __restrict__ rope){
  int i = blockIdx.x * blockDim.x + threadIdx.x;       // T * HDIM/2 = 2048*32
  if (i >= TSEQ * (HDIM/2)) return;
  int t = i >> 5, j = i & 31;
  float theta = exp2f(-(float)j * (13.287712379549449f / 32.f));
  float ang = (float)t * theta;
  rope[i] = make_float2(cosf(ang), sinf(ang));
}

// ---------------------------------------------------------------------------
// 128x256 tile GEMM, triple-buffered BK=64, counted vmcnt pipeline (verified).
// ---------------------------------------------------------------------------
#define AREG 8192    // u16 per A buf (128*64)
#define BREG 16384   // u16 per B buf (256*64)

__device__ __forceinline__ void gemm_tb3_mainloop(
    const u16* __restrict__ A, const u16* __restrict__ B,
    int m0, int n0, u16* sAb, u16* sBb, f32x4 acc[4][4])
{
  const int tid = threadIdx.x;
  const int lane = tid & 63, w = tid >> 6;
  const int ln = lane & 15, g = lane >> 4;
  const int wm = w >> 2, wn = w & 3;

  const f32x4 zero = {0.f, 0.f, 0.f, 0.f};
#pragma unroll
  for (int i = 0; i < 4; ++i)
#pragma unroll
    for (int nt = 0; nt < 4; ++nt) acc[i][nt] = zero;

  const int cA0 = tid,       rA0 = cA0 >> 3;
  const int cA1 = 512 + tid, rA1 = cA1 >> 3;
  const u16* aS0 = A + (size_t)(m0 + rA0)*CMODEL + (((cA0 & 7) ^ (rA0 & 7)) << 3);
  const u16* aS1 = A + (size_t)(m0 + rA1)*CMODEL + (((cA1 & 7) ^ (rA1 & 7)) << 3);
  const unsigned dA0 = (unsigned)cA0 * 8, dA1 = (unsigned)cA1 * 8;
  const u16* bS[4]; unsigned dB[4];
#pragma unroll
  for (int j = 0; j < 4; ++j){
    int c = j*512 + tid, r = c >> 3;
    bS[j] = B + (size_t)(n0 + r)*CMODEL + (((c & 7) ^ (r & 7)) << 3);
    dB[j] = (unsigned)c * 8;
  }

  unsigned aoff[4][2], boff[4][2];
#pragma unroll
  for (int i = 0; i < 4; ++i){
    int r = wm*64 + i*16 + ln;
#pragma unroll
    for (int kk = 0; kk < 2; ++kk)
      aoff[i][kk] = (unsigned)(r*8 + ((kk*4 + g) ^ (r & 7))) * 8;
  }
#pragma unroll
  for (int nt = 0; nt < 4; ++nt){
    int r = wn*64 + nt*16 + ln;
#pragma unroll
    for (int kk = 0; kk < 2; ++kk)
      boff[nt][kk] = (unsigned)(r*8 + ((kk*4 + g) ^ (r & 7))) * 8;
  }

  async16(aS0,       sAb + dA0);
  async16(aS1,       sAb + dA1);
  async16(bS[0],     sBb + dB[0]);
  async16(bS[1],     sBb + dB[1]);
  async16(bS[2],     sBb + dB[2]);
  async16(bS[3],     sBb + dB[3]);
  async16(aS0 + 64,  sAb + AREG + dA0);
  async16(aS1 + 64,  sAb + AREG + dA1);
  async16(bS[0] + 64, sBb + BREG + dB[0]);
  async16(bS[1] + 64, sBb + BREG + dB[1]);
  async16(bS[2] + 64, sBb + BREG + dB[2]);
  async16(bS[3] + 64, sBb + BREG + dB[3]);
  asm volatile("s_waitcnt vmcnt(6)" ::: "memory");
  asm volatile("s_barrier" ::: "memory");

#pragma unroll 1
  for (int kt = 0; kt < 16; ++kt){
    const int cb = kt % 3;
    const int nb = (kt + 2) % 3;
    const u16* Ab = sAb + cb*AREG;
    const u16* Bb = sBb + cb*BREG;
    u16* An = sAb + nb*AREG;
    u16* Bn = sBb + nb*BREG;
    const unsigned ko = (unsigned)(kt + 2) * 64u;
    const bool st = (kt < 14);

    bf16x8 a0, a1, a2, a3, b0, b1, b2, b3;

    a0 = *(const bf16x8*)&Ab[aoff[0][0]];
    a1 = *(const bf16x8*)&Ab[aoff[1][0]];
    b0 = *(const bf16x8*)&Bb[boff[0][0]];
    b1 = *(const bf16x8*)&Bb[boff[1][0]];
    b2 = *(const bf16x8*)&Bb[boff[2][0]];
    b3 = *(const bf16x8*)&Bb[boff[3][0]];
    if (st){ async16(aS0 + ko, An + dA0); async16(aS1 + ko, An + dA1); }
    asm volatile("s_barrier" ::: "memory");
    __builtin_amdgcn_s_setprio(1);
    acc[0][0] = __builtin_amdgcn_mfma_f32_16x16x32_bf16(a0, b0, acc[0][0], 0,0,0);
    acc[0][1] = __builtin_amdgcn_mfma_f32_16x16x32_bf16(a0, b1, acc[0][1], 0,0,0);
    acc[0][2] = __builtin_amdgcn_mfma_f32_16x16x32_bf16(a0, b2, acc[0][2], 0,0,0);
    acc[0][3] = __builtin_amdgcn_mfma_f32_16x16x32_bf16(a0, b3, acc[0][3], 0,0,0);
    acc[1][0] = __builtin_amdgcn_mfma_f32_16x16x32_bf16(a1, b0, acc[1][0], 0,0,0);
    acc[1][1] = __builtin_amdgcn_mfma_f32_16x16x32_bf16(a1, b1, acc[1][1], 0,0,0);
    acc[1][2] = __builtin_amdgcn_mfma_f32_16x16x32_bf16(a1, b2, acc[1][2], 0,0,0);
    acc[1][3] = __builtin_amdgcn_mfma_f32_16x16x32_bf16(a1, b3, acc[1][3], 0,0,0);
    __builtin_amdgcn_s_setprio(0);
    asm volatile("s_barrier" ::: "memory");

    a2 = *(const bf16x8*)&Ab[aoff[2][0]];
    a3 = *(const bf16x8*)&Ab[aoff[3][0]];
    if (st){ async16(bS[0] + ko, Bn + dB[0]); async16(bS[1] + ko, Bn + dB[1]); }
    asm volatile("s_barrier" ::: "memory");
    __builtin_amdgcn_s_setprio(1);
    acc[2][0] = __builtin_amdgcn_mfma_f32_16x16x32_bf16(a2, b0, acc[2][0], 0,0,0);
    acc[2][1] = __builtin_amdgcn_mfma_f32_16x16x32_bf16(a2, b1, acc[2][1], 0,0,0);
    acc[2][2] = __builtin_amdgcn_mfma_f32_16x16x32_bf16(a2, b2, acc[2][2], 0,0,0);
    acc[2][3] = __builtin_amdgcn_mfma_f32_16x16x32_bf16(a2, b3, acc[2][3], 0,0,0);
    acc[3][0] = __builtin_amdgcn_mfma_f32_16x16x32_bf16(a3, b0, acc[3][0], 0,0,0);
    acc[3][1] = __builtin_amdgcn_mfma_f32_16x16x32_bf16(a3, b1, acc[3][1], 0,0,0);
    acc[3][2] = __builtin_amdgcn_mfma_f32_16x16x32_bf16(a3, b2, acc[3][2], 0,0,0);
    acc[3][3] = __builtin_amdgcn_mfma_f32_16x16x32_bf16(a3, b3, acc[3][3], 0,0,0);
    __builtin_amdgcn_s_setprio(0);
    asm volatile("s_barrier" ::: "memory");

    a0 = *(const bf16x8*)&Ab[aoff[0][1]];
    a1 = *(const bf16x8*)&Ab[aoff[1][1]];
    b0 = *(const bf16x8*)&Bb[boff[0][1]];
    b1 = *(const bf16x8*)&Bb[boff[1][1]];
    b2 = *(const bf16x8*)&Bb[boff[2][1]];
    b3 = *(const bf16x8*)&Bb[boff[3][1]];
    if (st) async16(bS[2] + ko, Bn + dB[2]);
    asm volatile("s_barrier" ::: "memory");
    __builtin_amdgcn_s_setprio(1);
    acc[0][0] = __builtin_amdgcn_mfma_f32_16x16x32_bf16(a0, b0, acc[0][0], 0,0,0);
    acc[0][1] = __builtin_amdgcn_mfma_f32_16x16x32_bf16(a0, b1, acc[0][1], 0,0,0);
    acc[0][2] = __builtin_amdgcn_mfma_f32_16x16x32_bf16(a0, b2, acc[0][2], 0,0,0);
    acc[0][3] = __builtin_amdgcn_mfma_f32_16x16x32_bf16(a0, b3, acc[0][3], 0,0,0);
    acc[1][0] = __builtin_amdgcn_mfma_f32_16x16x32_bf16(a1, b0, acc[1][0], 0,0,0);
    acc[1][1] = __builtin_amdgcn_mfma_f32_16x16x32_bf16(a1, b1, acc[1][1], 0,0,0);
    acc[1][2] = __builtin_amdgcn_mfma_f32_16x16x32_bf16(a1, b2, acc[1][2], 0,0,0);
    acc[1][3] = __builtin_amdgcn_mfma_f32_16x16x32_bf16(a1, b3, acc[1][3], 0,0,0);
    __builtin_amdgcn_s_setprio(0);
    asm volatile("s_barrier" ::: "memory");

    a2 = *(const bf16x8*)&Ab[aoff[2][1]];
    a3 = *(const bf16x8*)&Ab[aoff[3][1]];
    if (st) async16(bS[3] + ko, Bn + dB[3]);
    asm volatile("s_barrier" ::: "memory");
    __builtin_amdgcn_s_setprio(1);
    acc[2][0] = __builtin_amdgcn_mfma_f32_16x16x32_bf16(a2, b0, acc[2][0], 0,0,0);
    acc[2][1] = __builtin_amdgcn_mfma_f32_16x16x32_bf16(a2, b1, acc[2][1], 0,0,0);
    acc[2][2] = __builtin_amdgcn_mfma_f32_16x16x32_bf16(a2, b2, acc[2][2], 0,0,0);
    acc[2][3] = __builtin_amdgcn_mfma_f32_16x16x32_bf16(a2, b3, acc[2][3], 0,0,0);
    acc[3][0] = __builtin_amdgcn_mfma_f32_16x16x32_bf16(a3, b0, acc[3][0], 0,0,0);
    acc[3][1] = __builtin_amdgcn_mfma_f32_16x16x32_bf16(a3, b1, acc[3][1], 0,0,0);
    acc[3][2] = __builtin_amdgcn_mfma_f32_16x16x32_bf16(a3, b2, acc[3][2], 0,0,0);
    acc[3][3] = __builtin_amdgcn_mfma_f32_16x16x32_bf16(a3, b3, acc[3][3], 0,0,0);
    __builtin_amdgcn_s_setprio(0);
    if (st) asm volatile("s_waitcnt vmcnt(6)" ::: "memory");
    else    asm volatile("s_waitcnt vmcnt(0)" ::: "memory");
    asm volatile("s_barrier" ::: "memory");
  }
}

// ---------------------------------------------------------------------------
// QKV projection (128x256 tb3) + bias + RoPE(Q,K) + head-split; V transposed.
// ---------------------------------------------------------------------------
#define SCQ 0.18033688011112042f   // 0.125 * log2(e)

__global__ __launch_bounds__(512, 1) void gemm_qkv_kernel(
    const u16* __restrict__ xb,
    const u16* __restrict__ wqb, const u16* __restrict__ wkb, const u16* __restrict__ wvb,
    const float* __restrict__ bq, const float* __restrict__ bk, const float* __restrict__ bv,
    const float2* __restrict__ rope,
    u16* __restrict__ Qh, u16* __restrict__ Kh, u16* __restrict__ Vt)
{
  __shared__ u16 sA[3*AREG];
  __shared__ u16 sB[3*BREG];
  const int z = blockIdx.z;
  const u16*  W    = (z == 0) ? wqb : (z == 1) ? wkb : wvb;
  const float* bias = (z == 0) ? bq  : (z == 1) ? bk  : bv;
  const int m0 = blockIdx.y * 128, n0 = blockIdx.x * 256;

  f32x4 acc[4][4];
  gemm_tb3_mainloop(xb, W, m0, n0, sA, sB, acc);

  const int tid = threadIdx.x, w = tid >> 6, lane = tid & 63;
  const int ln = lane & 15, g = lane >> 4;
  const int wm = w >> 2, wn = w & 3;

#pragma unroll
  for (int mt = 0; mt < 4; ++mt){
#pragma unroll
    for (int nt = 0; nt < 4; ++nt){
      int o  = n0 + wn*64 + nt*16 + ln;    // output feature 0..1023
      float bb = bias[o];
      int h  = o >> 6;
      int dd = o & 63;
      if (z < 2){
        int j = dd >> 1;
        u16* dst = (z == 0) ? Qh : Kh;
        float qs = (z == 0) ? SCQ : 1.0f;
#pragma unroll
        for (int rr = 0; rr < 4; ++rr){
          int t  = m0 + wm*64 + mt*16 + g*4 + rr;   // global token
          int b  = t >> 11, tt = t & (TSEQ-1);
          float v  = acc[mt][nt][rr] + bb;
          float pv = __shfl_xor(v, 1);              // rope partner (o^1), same row
          float2 cs = rope[tt*32 + j];
          float out = ((o & 1) == 0) ? (v*cs.x - pv*cs.y) : (pv*cs.y + v*cs.x);
          dst[(size_t)((b*NHEAD + h)*TSEQ + tt)*HDIM + dd] = f2bf(out * qs);
        }
      } else {
        int t0 = m0 + wm*64 + mt*16 + g*4;
        int b  = t0 >> 11, tt0 = t0 & (TSEQ-1);
        u16 pk[4];
#pragma unroll
        for (int rr = 0; rr < 4; ++rr) pk[rr] = f2bf(acc[mt][nt][rr] + bb);
        *(ushort4*)&Vt[(size_t)((b*NHEAD + h)*HDIM + dd)*TSEQ + tt0] =
            make_ushort4(pk[0], pk[1], pk[2], pk[3]);
      }
    }
  }
}

// ---------------------------------------------------------------------------
// Flash attention v14 — 8-wave blocks, ONE 256-row supertile per block.
//  - 512 blocks (64 bh x 8 supertiles); LPT: s = 7-(bid>>6) so longest first;
//    XCD grouping: bh = (bid&7)*8 + ((bid>>3)&7) -> the 8 bh of one XCD slot
//    share that XCD's L2 (KV working set ~4MB).
//  - 48KB LDS -> 2 blocks/CU co-resident: stalls of one block overlap the
//    other's compute (the lever rounds 13/14 lacked at 1 block/CU).
//  - KVBLK=64, triple-buffered, counted vmcnt(2) ledger; per-wave math =
//    verified v13 (swapped 32x32 MFMA, in-register softmax, defer-max,
//    cvt_pk+permlane pack; diag jtw = 4s+(w>>1), wodd=w&1).
// ---------------------------------------------------------------------------
__global__ __launch_bounds__(512, 4) void attn_kernel(
    const u16* __restrict__ Qh, const u16* __restrict__ Kh,
    const u16* __restrict__ Vt, u16* __restrict__ yb)
{
  __shared__ u16 sK[3][64*64];
  __shared__ u16 sV[3][64*64];

  const int tid = threadIdx.x, w = tid >> 6, lane = tid & 63;
  const int ln = lane & 31, hi = lane >> 5;

  const int bid = blockIdx.x;                  // 0..511
  const int s   = 7 - (bid >> 6);              // supertile 0..7, longest first
  const int bh  = (bid & 7) * 8 + ((bid >> 3) & 7);
  const int b   = bh >> 4, h = bh & (NHEAD-1);

  const u16* Qbase = Qh + (size_t)bh * TSEQ * HDIM;
  const u16* Kbase = Kh + (size_t)bh * TSEQ * HDIM;
  const u16* Vbase = Vt + (size_t)bh * HDIM * TSEQ;

  // staging: thread stages chunk tid of K tile and of V tile (8KB each)
  const int cr = tid >> 3, cs = tid & 7;
  const u16* kp = Kbase + (size_t)cr*HDIM + ((cs ^ (cr&7))<<3);
  const u16* vp = Vbase + (size_t)cr*TSEQ + ((cs ^ (cr&7))<<3);
  const unsigned dstw = (unsigned)(w*64)*8;    // wave-uniform LDS base (u16)

  // frag read offsets (u16 units), rows are 64-u16 wide
  const int swz = ln & 7;
  unsigned offd[4];
#pragma unroll
  for (int d = 0; d < 4; ++d) offd[d] = ((unsigned)((2*d + hi) ^ swz)) * 8;
  const unsigned rowl = (unsigned)ln * 64;
  const unsigned rowh = rowl + 32*64;

  const f32x16 zero16 = {0,0,0,0,0,0,0,0,0,0,0,0,0,0,0,0};
  const int wodd = w & 1;

  const int r0  = s*256 + w*32;                // wave's first q-row
  const int jtb = 4*s + 3;                     // supertile's last kv-tile
  const int jtw = 4*s + (w >> 1);              // wave's diagonal kv-tile

  // Q fragments
  bf16x8 qf[4];
#pragma unroll
  for (int ds = 0; ds < 4; ++ds)
    qf[ds] = *(const bf16x8*)&Qbase[(size_t)(r0 + ln)*HDIM + ds*16 + hi*8];

  f32x16 yacc0 = zero16, yacc1 = zero16;
  float m2 = -1e30f, lp = 0.f;

  // prologue: stage tiles 0,1 -> bufs 0,1  (jtb >= 3 always)
  async16(kp,                   sK[0] + dstw);
  async16(vp,                   sV[0] + dstw);
  async16(kp + (size_t)64*HDIM, sK[1] + dstw);
  async16(vp + 64,              sV[1] + dstw);
  asm volatile("s_waitcnt vmcnt(2)" ::: "memory");
  asm volatile("s_barrier" ::: "memory");

#pragma unroll 1
  for (int jt = 0; jt <= jtb; ++jt){
    // stage jt+2 into buf (jt+2)%3
    const bool st2 = (jt + 2 <= jtb);
    if (st2){
      const int nb = (jt + 2) % 3;
      async16(kp + (size_t)(jt+2)*64*HDIM, sK[nb] + dstw);
      async16(vp + (size_t)(jt+2)*64,      sV[nb] + dstw);
    }

    if (jt <= jtw){
      const int cb = jt % 3;
      const u16* sKb = sK[cb];
      const u16* sVb = sV[cb];
      const bool full1 = (jt < jtw) || wodd;

      // ---- QK^T (swapped): p0 = kv rows 0..31, p1 = 32..63 ----
      f32x16 p0 = zero16, p1 = zero16;
      __builtin_amdgcn_s_setprio(1);
#pragma unroll
      for (int ds = 0; ds < 4; ++ds){
        bf16x8 k0 = *(const bf16x8*)&sKb[rowl + offd[ds]];
        p0 = __builtin_amdgcn_mfma_f32_32x32x16_bf16(k0, qf[ds], p0, 0, 0, 0);
      }
      if (full1){
#pragma unroll
        for (int ds = 0; ds < 4; ++ds){
          bf16x8 k1 = *(const bf16x8*)&sKb[rowh + offd[ds]];
          p1 = __builtin_amdgcn_mfma_f32_32x32x16_bf16(k1, qf[ds], p1, 0, 0, 0);
        }
      }
      __builtin_amdgcn_s_setprio(0);

      // ---- causal mask on the wave's diag tile ----
      if (jt == jtw){
#pragma unroll
        for (int r = 0; r < 16; ++r){
          int k0r = (r&3) + 8*(r>>2) + 4*hi;
          bool cut = k0r > ln;
          if (!wodd){ if (cut) p0[r] = -1e30f; }
          else      { if (cut) p1[r] = -1e30f; }
        }
      }

      // ---- lane-local row max ----
      float lm = p0[0];
#pragma unroll
      for (int r = 1; r < 16; ++r) lm = fmaxf(lm, p0[r]);
      if (full1){
#pragma unroll
        for (int r = 0; r < 16; ++r) lm = fmaxf(lm, p1[r]);
      }

      // defer-max
      if (__any(lm - m2 > 8.0f)){
        float lmp = __shfl_xor(lm, 32);
        float mn  = fmaxf(m2, fmaxf(lm, lmp));
        float scl = exp2f(m2 - mn);
        m2 = mn;
        lp *= scl;
#pragma unroll
        for (int r = 0; r < 16; ++r){
          float sr = __shfl(scl, (r&3) + 8*(r>>2) + 4*hi);
          yacc0[r] *= sr; yacc1[r] *= sr;
        }
      }

      // ---- exp + per-lane partial sum ----
      float ts = 0.f;
#pragma unroll
      for (int r = 0; r < 16; ++r){ p0[r] = exp2f(p0[r] - m2); ts += p0[r]; }
      if (full1){
#pragma unroll
        for (int r = 0; r < 16; ++r){ p1[r] = exp2f(p1[r] - m2); ts += p1[r]; }
      }
      lp += ts;

      // ---- pack P into PV A-fragments ----
      bf16x8 pa[4];
      {
        union { unsigned u[4]; bf16x8 v; } f0, f1;
        unsigned A0 = cvtpk(p0[0], p0[1]),  B0 = cvtpk(p0[2], p0[3]);
        unsigned A1 = cvtpk(p0[4], p0[5]),  B1 = cvtpk(p0[6], p0[7]);
        plswap(A0, A1); plswap(B0, B1);
        f0.u[0]=A0; f0.u[1]=B0; f0.u[2]=A1; f0.u[3]=B1;  pa[0]=f0.v;
        unsigned A2 = cvtpk(p0[8], p0[9]),  B2 = cvtpk(p0[10], p0[11]);
        unsigned A3 = cvtpk(p0[12], p0[13]),B3 = cvtpk(p0[14], p0[15]);
        plswap(A2, A3); plswap(B2, B3);
        f1.u[0]=A2; f1.u[1]=B2; f1.u[2]=A3; f1.u[3]=B3;  pa[1]=f1.v;
      }
      if (full1){
        union { unsigned u[4]; bf16x8 v; } f2, f3;
        unsigned A4 = cvtpk(p1[0], p1[1]),  B4 = cvtpk(p1[2], p1[3]);
        unsigned A5 = cvtpk(p1[4], p1[5]),  B5 = cvtpk(p1[6], p1[7]);
        plswap(A4, A5); plswap(B4, B5);
        f2.u[0]=A4; f2.u[1]=B4; f2.u[2]=A5; f2.u[3]=B5;  pa[2]=f2.v;
        unsigned A6 = cvtpk(p1[8], p1[9]),  B6 = cvtpk(p1[10], p1[11]);
        unsigned A7 = cvtpk(p1[12], p1[13]),B7 = cvtpk(p1[14], p1[15]);
        plswap(A6, A7); plswap(B6, B7);
        f3.u[0]=A6; f3.u[1]=B6; f3.u[2]=A7; f3.u[3]=B7;  pa[3]=f3.v;
      }

      // ---- PV ----
      __builtin_amdgcn_s_setprio(1);
#pragma unroll
      for (int st = 0; st < 2; ++st){
        bf16x8 v0 = *(const bf16x8*)&sVb[rowl + offd[st]];
        bf16x8 v1 = *(const bf16x8*)&sVb[rowh + offd[st]];
        yacc0 = __builtin_amdgcn_mfma_f32_32x32x16_bf16(pa[st], v0, yacc0, 0, 0, 0);
        yacc1 = __builtin_amdgcn_mfma_f32_32x32x16_bf16(pa[st], v1, yacc1, 0, 0, 0);
      }
      if (full1){
#pragma unroll
        for (int st = 2; st < 4; ++st){
          bf16x8 v0 = *(const bf16x8*)&sVb[rowl + offd[st]];
          bf16x8 v1 = *(const bf16x8*)&sVb[rowh + offd[st]];
          yacc0 = __builtin_amdgcn_mfma_f32_32x32x16_bf16(pa[st], v0, yacc0, 0, 0, 0);
          yacc1 = __builtin_amdgcn_mfma_f32_32x32x16_bf16(pa[st], v1, yacc1, 0, 0, 0);
        }
      }
      __builtin_amdgcn_s_setprio(0);
    }

    // ledger: ensure stage(jt+1) landed before next iter; never 0 until tail
    if (st2) asm volatile("s_waitcnt vmcnt(2)" ::: "memory");
    else     asm volatile("s_waitcnt vmcnt(0)" ::: "memory");
    asm volatile("s_barrier" ::: "memory");
  }

  // ---- epilogue: full row sum, divide, write [token][C] bf16 ----
  float lpf = lp + __shfl_xor(lp, 32);
  float inv = 1.0f / lpf;
#pragma unroll
  for (int r = 0; r < 16; ++r){
    int q = (r&3) + 8*(r>>2) + 4*hi;
    float ir = __shfl(inv, q);
    int tt = r0 + q;
    size_t rowoff = (size_t)(b*TSEQ + tt)*CMODEL + h*HDIM;
    yb[rowoff + ln]      = f2bf(yacc0[r] * ir);
    yb[rowoff + 32 + ln] = f2bf(yacc1[r] * ir);
  }
}

// ---------------------------------------------------------------------------
// output projection (128x256 tb3), f32 result straight to d_out
// ---------------------------------------------------------------------------
__global__ __launch_bounds__(512, 1) void gemm_proj_kernel(
    const u16* __restrict__ yb, const u16* __restrict__ wpb,
    const float* __restrict__ bp, float* __restrict__ out)
{
  __shared__ u16 sA[3*AREG];
  __shared__ u16 sB[3*BREG];
  const int m0 = blockIdx.y * 128, n0 = blockIdx.x * 256;
  f32x4 acc[4][4];
  gemm_tb3_mainloop(yb, wpb, m0, n0, sA, sB, acc);

  const int tid = threadIdx.x, w = tid >> 6, lane = tid & 63;
  const int ln = lane & 15, g = lane >> 4;
  const int wm = w >> 2, wn = w & 3;
#pragma unroll
  for (int mt = 0; mt < 4; ++mt)
#pragma unroll
    for (int nt = 0; nt < 4; ++nt){
      int o = n0 + wn*64 + nt*16 + ln;
      float bb = bp[o];
#pragma unroll
      for (int rr = 0; rr < 4; ++rr){
        int t = m0 + wm*64 + mt*16 + g*4 + rr;
        out[(size_t)t*CMODEL + o] = acc[mt][nt][rr] + bb;
      }
    }
}

// ---------------------------------------------------------------------------
extern "C" void kernel_launch(void* const* d_in, const int* in_sizes, int n_in,
                              void* d_out, int out_size, void* d_ws, size_t ws_size,
                              hipStream_t stream)
{
  const float* x  = (const float*)d_in[0];
  const float* wq = (const float*)d_in[1];
  const float* bq = (const float*)d_in[2];
  const float* wk = (const float*)d_in[3];
  const float* bk = (const float*)d_in[4];
  const float* wv = (const float*)d_in[5];
  const float* bv = (const float*)d_in[6];
  const float* wp = (const float*)d_in[7];
  const float* bp = (const float*)d_in[8];

  char* ws = (char*)d_ws;
  u16*    xb   = (u16*)   (ws + 0);           // 16 MiB
  u16*    wqb  = (u16*)   (ws + 16777216);    // 2 MiB
  u16*    wkb  = (u16*)   (ws + 18874368);
  u16*    wvb  = (u16*)   (ws + 20971520);
  u16*    wpb  = (u16*)   (ws + 23068672);
  float2* rope = (float2*)(ws + 25165824);    // 512 KiB
  u16*    Qh   = (u16*)   (ws + 25690112);    // 16 MiB  [bh][t][d]
  u16*    Kh   = (u16*)   (ws + 42467328);    // 16 MiB  [bh][t][d]
  u16*    Vt   = (u16*)   (ws + 59244544);    // 16 MiB  [bh][d][t]
  u16*    yb   = (u16*)   (ws + 76021760);    // 16 MiB  [token][C]

  cast_bf16_kernel<<<2048, 256, 0, stream>>>(x,  xb,  MTOK*CMODEL/4);
  cast4_bf16_kernel<<<dim3(256, 4), 256, 0, stream>>>(wq, wk, wv, wp, wqb, wkb, wvb, wpb,
                                                      CMODEL*CMODEL/4);
  rope_table_kernel<<<(TSEQ*(HDIM/2) + 255)/256, 256, 0, stream>>>(rope);

  gemm_qkv_kernel<<<dim3(CMODEL/256, MTOK/128, 3), 512, 0, stream>>>(
      xb, wqb, wkb, wvb, bq, bk, bv, rope, Qh, Kh, Vt);

  attn_kernel<<<dim3(512), 512, 0, stream>>>(Qh, Kh, Vt, yb);

  gemm_proj_kernel<<<dim3(CMODEL/256, MTOK/128), 512, 0, stream>>>(yb, wpb, bp, (float*)d_out);
}